// Round 6
// baseline (239.311 us; speedup 1.0000x reference)
//
#include <hip/hip_runtime.h>

#define ROWLEN 4096
#define TPB    256
#define RPB    4                 // rows per block, processed pipelined
#define LOG2E  1.44269504088896340736f

typedef float f32x4 __attribute__((ext_vector_type(4)));

__device__ __forceinline__ float exp2_fast(float x){float r;asm("v_exp_f32 %0, %1":"=v"(r):"v"(x));return r;}
__device__ __forceinline__ float rcp_fast (float x){float r;asm("v_rcp_f32 %0, %1":"=v"(r):"v"(x));return r;}
__device__ __forceinline__ float log2_fast(float x){float r;asm("v_log_f32 %0, %1":"=v"(r):"v"(x));return r;}
__device__ __forceinline__ float sqrt_fast(float x){float r;asm("v_sqrt_f32 %0, %1":"=v"(r):"v"(x));return r;}

// Reduce barrier WITHOUT vmcnt(0) drain (unlike __syncthreads): only the
// ds_write must be visible; prefetch loads / NT stores stay in flight.
__device__ __forceinline__ void red_barrier() {
    asm volatile("s_waitcnt lgkmcnt(0)" ::: "memory");
    __builtin_amdgcn_s_barrier();
}

__device__ __forceinline__ void load_row(const float* __restrict__ x, size_t row,
                                         int t, float (&buf)[16]) {
    const f32x4* rp = reinterpret_cast<const f32x4*>(x + row * ROWLEN);
#pragma unroll
    for (int k = 0; k < 4; ++k) {
        f32x4 f = rp[k * TPB + t];
        buf[4*k+0]=f.x; buf[4*k+1]=f.y; buf[4*k+2]=f.z; buf[4*k+3]=f.w;
    }
}

// buf holds x on entry, E = e^x after sweep A (in place). Solves sum sigma = 64
// in t = e^nu space (same math as the R5-passing kernel + proper disc fallback).
__device__ __forceinline__ void process_row(float (&E)[16], float* __restrict__ outp,
                                            int t, float (*red)[16], int rbase) {
    const int lane = t & 63, wave = t >> 6;

    // ---- sweep A: E = exp(x) in place; S1 = sum E, S2 = sum E^2, mn = min E ----
    float s1a=0, s1b=0, s2a=0, s2b=0, mna=3.4e38f, mnb=3.4e38f;
#pragma unroll
    for (int i = 0; i < 16; i += 2) {
        float e0 = exp2_fast(E[i]   * LOG2E);
        float e1 = exp2_fast(E[i+1] * LOG2E);
        E[i] = e0; E[i+1] = e1;
        s1a += e0; s1b += e1;
        s2a = fmaf(e0, e0, s2a); s2b = fmaf(e1, e1, s2b);
        mna = fminf(mna, e0);    mnb = fminf(mnb, e1);
    }
    float S1 = s1a + s1b, S2 = s2a + s2b, mn = fminf(mna, mnb);
#pragma unroll
    for (int off = 32; off >= 1; off >>= 1) {
        S1 += __shfl_xor(S1, off, 64);
        S2 += __shfl_xor(S2, off, 64);
        mn = fminf(mn, __shfl_xor(mn, off, 64));
    }
    if (lane == 0) { float* s = red[rbase] + wave * 4; s[0]=S1; s[1]=S2; s[2]=mn; }
    red_barrier();
    {
        const float* s = red[rbase];
        S1 = (s[0]+s[4]) + (s[8]+s[12]);
        S2 = (s[1]+s[5]) + (s[9]+s[13]);
        mn = fminf(fminf(s[2],s[6]), fminf(s[10],s[14]));
    }

    // ---- two-sided bracket in t = e^nu ----
    // sigma(z) <= e^z          => tl = 64/S1 is a lower bracket
    // sigma(z) >= e^z - e^{2z} => t_quad = 128/(S1+sqrt(S1^2-256*S2)) upper (disc>0)
    // fallback upper: t = 1/min(E)  (element at min x has sigma = 0.5 => sum >= 64)
    float disc = fmaf(S1, S1, -256.0f * S2);
    float tl = 64.0f * rcp_fast(S1);
    float th = (disc > 0.0f) ? 128.0f * rcp_fast(S1 + sqrt_fast(disc)) : rcp_fast(mn);
    float tt = sqrt_fast(tl * th);   // geometric mid == arithmetic mid in nu-space

    // ---- 2 safeguarded log-space Newton sweeps (no exp in the sweep!) ----
#pragma unroll 1
    for (int it = 0; it < 2; ++it) {
        float fa=0, fb=0, wa=0, wb=0;
#pragma unroll
        for (int i = 0; i < 16; i += 2) {
            float u0 = E[i] * tt,            u1 = E[i+1] * tt;
            float r0 = rcp_fast(1.0f + u0),  r1 = rcp_fast(1.0f + u1);
            float g0 = u0 * r0,              g1 = u1 * r1;      // sigma
            fa += g0; fb += g1;
            wa = fmaf(g0, r0, wa); wb = fmaf(g1, r1, wb);       // sigma*(1-sigma)
        }
        float fs = fa + fb, fw = wa + wb;
#pragma unroll
        for (int off = 32; off >= 1; off >>= 1) {
            fs += __shfl_xor(fs, off, 64);
            fw += __shfl_xor(fw, off, 64);
        }
        if (lane == 0) { float* s = red[rbase+1] + wave*4 + it*2; s[0]=fs; s[1]=fw; }
        red_barrier();
        {
            const float* s = red[rbase+1] + it*2;
            fs = (s[0]+s[4]) + (s[8]+s[12]);
            fw = (s[1]+s[5]) + (s[9]+s[13]);
        }
        if (fs < 64.0f) tl = tt; else th = tt;      // keep valid bracket
        // t' = t * (64/fs)^(fs/fw)  (log-space Newton)
        float step = (6.0f - log2_fast(fs)) * fs * rcp_fast(fw);
        float tn = tt * exp2_fast(step);
        tt = (tn > tl && tn < th) ? tn : sqrt_fast(tl * th);
    }

    // ---- output sweep: sigma = u/(1+u), NT store ----
#pragma unroll
    for (int k = 0; k < 4; ++k) {
        f32x4 f;
#pragma unroll
        for (int j = 0; j < 4; ++j) {
            float u = E[4*k+j] * tt;
            f[j] = u * rcp_fast(1.0f + u);
        }
        __builtin_nontemporal_store(f, reinterpret_cast<f32x4*>(outp) + k * TPB + t);
    }
}

__global__ __launch_bounds__(TPB) void lml_kernel(const float* __restrict__ x,
                                                  float* __restrict__ out) {
    const int t = threadIdx.x;
    __shared__ float red[2 * RPB][16];
    const size_t r0 = (size_t)blockIdx.x * RPB;
    float A[16], B[16];

    // software pipeline: load next row while processing current; stores fire-and-forget
    load_row(x, r0 + 0, t, A);
    load_row(x, r0 + 1, t, B);
    process_row(A, out + (r0 + 0) * ROWLEN, t, red, 0);
    load_row(x, r0 + 2, t, A);
    process_row(B, out + (r0 + 1) * ROWLEN, t, red, 2);
    load_row(x, r0 + 3, t, B);
    process_row(A, out + (r0 + 2) * ROWLEN, t, red, 4);
    process_row(B, out + (r0 + 3) * ROWLEN, t, red, 6);
}

extern "C" void kernel_launch(void* const* d_in, const int* in_sizes, int n_in,
                              void* d_out, int out_size, void* d_ws, size_t ws_size,
                              hipStream_t stream) {
    const float* x = (const float*)d_in[0];
    float* out = (float*)d_out;
    const int rows = in_sizes[0] / ROWLEN;        // 8192
    lml_kernel<<<rows / RPB, TPB, 0, stream>>>(x, out);
}